// Round 1
// baseline (107.747 us; speedup 1.0000x reference)
//
#include <hip/hip_runtime.h>
#include <float.h>
#include <math.h>

// Problem constants (from reference setup_inputs)
#define B_ 4
#define N_ 4096
#define K_ 2048
#define TPB 256

// R8 structure: register-blocked rows to cut LDS-read traffic (the measured
// bottleneck: 1.74 GB LDS reads @ ~70% of ds_read_b128 ceiling in R7).
//   role-3: 4 rows/thread, 64 rows/block, 256 blocks  (16 B -> 4 B per pair)
//   chamfer: 8 rows/thread, 128 rows/block, 128 blocks per direction
//   coverage: 8 rows/thread, 128 rows/block, 64 blocks
#define R3_NB 256
#define CD_NB 128
#define COV_NB 64
#define MIN_NB (2 * CD_NB + COV_NB)  // 320
#define GRID (R3_NB + MIN_NB)        // 576

// ws partial-sum layout (floats); every slot written every call -> no zeroing
#define WS_REP 0      // 256
#define WS_SMO 256    // 256
#define WS_CD1 512    // 128
#define WS_CD2 640    // 128
#define WS_COV 768    // 64

// Padded tile: 16 groups x 65 float4 (4 distinct banks per wave, broadcast
// within each 16-lane group).
#define GPAD 65
// role-3 merge area: 64 rows x 16 lists; 8-lists at stride 9, L1 merges pairs
// in place to 16-lists at stride 18. 64*144 = 9216, + 64 aa = 9280 floats.
#define AA_OFF 9216
#define SMEM_F 9280

__device__ inline float wave_sum(float v) {
#pragma unroll
  for (int off = 32; off > 0; off >>= 1) v += __shfl_down(v, off, 64);
  return v;
}

__device__ inline void ce_asc(float& a, float& b) {
  float lo = fminf(a, b), hi = fmaxf(a, b);
  a = lo; b = hi;
}
__device__ inline void ce_desc(float& a, float& b) {
  float lo = fminf(a, b), hi = fmaxf(a, b);
  a = hi; b = lo;
}

// Batcher odd-even mergesort of 8, DESCENDING: 19 CEs (validated R6)
__device__ inline void bsort8_desc(float (&v)[8]) {
#define CE(i, j) ce_desc(v[i], v[j])
  CE(0,1); CE(2,3); CE(4,5); CE(6,7);
  CE(0,2); CE(1,3); CE(4,6); CE(5,7);
  CE(1,2); CE(5,6);
  CE(0,4); CE(1,5); CE(2,6); CE(3,7);
  CE(2,4); CE(3,5);
  CE(1,2); CE(3,4); CE(5,6);
#undef CE
}

// bitonic 8-sequence cleanup to ascending (3 stages, 12 CEs)
__device__ inline void bitonic_merge8_asc(float (&v)[8]) {
#pragma unroll
  for (int j = 4; j > 0; j >>= 1) {
#pragma unroll
    for (int i = 0; i < 8; ++i) {
      int ixj = i ^ j;
      if (ixj > i) ce_asc(v[i], v[ixj]);
    }
  }
}

// bitonic 16-sequence cleanup to ascending (4 stages, 32 CEs)
__device__ inline void bitonic_merge16_asc(float (&v)[16]) {
#pragma unroll
  for (int j = 8; j > 0; j >>= 1) {
#pragma unroll
    for (int i = 0; i < 16; ++i) {
      int ixj = i ^ j;
      if (ixj > i) ce_asc(v[i], v[ixj]);
    }
  }
}

// L1: two ascending 8-lists at A[0..7] and A[9..16] -> full ascending 16 at
// A[0..15] (in place; task region is 18 floats, reads complete before writes).
__device__ inline void fullmerge8_inplace(float* A) {
  float m[16];
#pragma unroll
  for (int i = 0; i < 8; ++i) m[i] = A[i];
#pragma unroll
  for (int i = 0; i < 8; ++i) m[8 + i] = A[9 + 7 - i];  // asc then desc = bitonic
  bitonic_merge16_asc(m);
#pragma unroll
  for (int i = 0; i < 16; ++i) A[i] = m[i];
}

// merge two ascending-16 lists -> 16 smallest ascending, stored to A
__device__ inline void keep16_lds(float* A, const float* Bl) {
  float m[16];
#pragma unroll
  for (int i = 0; i < 16; ++i) m[i] = fminf(A[i], Bl[15 - i]);
  bitonic_merge16_asc(m);
#pragma unroll
  for (int i = 0; i < 16; ++i) A[i] = m[i];
}

// Distances via s' = |c|^2 - 2 a.c (LDS tile stores (x,y,z,|c|^2));
// |a|^2 added back after selection (monotone shift). Validated since R3.
// Role-3 keeps per-thread top-8 over 256 cands (16 threads/row): row top-8
// provably exact; ranks 9-16 exact unless one thread holds >=9 of the row's
// top-16 (P~3e-6/row, error ~1e-7 if fired). Unchanged from R7.
__global__ __launch_bounds__(TPB, 3) void fused_loss(const float* __restrict__ pred,
                                                     const float* __restrict__ gt,
                                                     const float* __restrict__ partial,
                                                     float* __restrict__ ws) {
  // union: padded tile (16*65 float4 = 4160 f) / role-3 merge lists (9280 f)
  // / min-role cross-group area (128*17 + 2 = 2178 f)
  __shared__ __align__(16) float smem_f[SMEM_F];
  float4* tile = reinterpret_cast<float4*>(smem_f);

  const int blk = blockIdx.x;
  const int t = threadIdx.x;
  const int r = t & 15;   // row slot
  const int g = t >> 4;   // column group (16 groups of 64 cols per 1024-tile)
  const int base = g * GPAD;

  // Static load-balance remap. Model: blk and blk+256 land on the same CU
  // (8-XCD round-robin, 32 CU/XCD). Grid = 2.25 blocks/CU; naive order gives
  // 64 CUs {R3+CD+COV} ~57K cyc vs 41K elsewhere. Remap: 64 CUs take 3 min
  // blocks (~50K), 64 take 2 R3 (~48K), 128 take R3+min (~41K). If the
  // mapping model is wrong this is merely a permutation (correctness-neutral).
  const int cuid = blk & 255, rnd = blk >> 8;
  int vb;
  if (cuid < 64)      vb = R3_NB + rnd * 64 + cuid;     // min ids 0..191
  else if (rnd == 0)  vb = cuid - 64;                   // R3 ids 0..191
  else if (cuid < 128) vb = 192 + (cuid - 64);          // R3 ids 192..255
  else                vb = R3_NB + 192 + (cuid - 128);  // min ids 192..319

  if (vb < R3_NB) {
    // ================= role 3: pred self top-16 =================
    // 64 rows/block, 4 rows/thread; each float4 LDS read feeds 4 rows.
    const int rid = vb;
    const int b = rid >> 6;
    const int row0 = (rid & 63) * 64;
    const size_t cbase = (size_t)b * N_ * 3;

    float nx[4], ny[4], nz[4], aa4[4];
#pragma unroll
    for (int q = 0; q < 4; ++q) {
      const size_t p = cbase + (size_t)(row0 + q * 16 + r) * 3;
      const float x = pred[p], y = pred[p + 1], z = pred[p + 2];
      aa4[q] = fmaf(x, x, fmaf(y, y, z * z));
      nx[q] = -2.f * x; ny[q] = -2.f * y; nz[q] = -2.f * z;
    }

    float t8[4][8];
#pragma unroll
    for (int q = 0; q < 4; ++q)
#pragma unroll
      for (int i = 0; i < 8; ++i) t8[q][i] = FLT_MAX;

    // T14 prefetch: next tile's 4 points live in regs while current computes.
    float px[4], py[4], pz[4], qx[4], qy[4], qz[4];
#pragma unroll
    for (int k = 0; k < 4; ++k) {
      const size_t p = cbase + 3 * (size_t)(t + k * 256);
      px[k] = pred[p]; py[k] = pred[p + 1]; pz[k] = pred[p + 2];
    }

#pragma unroll 1
    for (int T = 0; T < 4; ++T) {
      __syncthreads();
#pragma unroll
      for (int k = 0; k < 4; ++k) {
        const int i = t + k * 256;
        tile[(i >> 6) * GPAD + (i & 63)] =
            make_float4(px[k], py[k], pz[k],
                        fmaf(px[k], px[k], fmaf(py[k], py[k], pz[k] * pz[k])));
      }
      if (T < 3) {  // issue next-tile loads; latency hides under compute
#pragma unroll
        for (int k = 0; k < 4; ++k) {
          const size_t p = cbase + 3 * (size_t)((T + 1) * 1024 + t + k * 256);
          qx[k] = pred[p]; qy[k] = pred[p + 1]; qz[k] = pred[p + 2];
        }
      }
      __syncthreads();

#pragma unroll 1
      for (int jb = 0; jb < 64; jb += 8) {
        float4 c[8];
#pragma unroll
        for (int u = 0; u < 8; ++u) c[u] = tile[base + jb + u];
#pragma unroll
        for (int q = 0; q < 4; ++q) {
          float s[8];
#pragma unroll
          for (int u = 0; u < 8; ++u)
            s[u] = fmaf(nx[q], c[u].x, fmaf(ny[q], c[u].y, fmaf(nz[q], c[u].z, c[u].w)));
          bsort8_desc(s);
          // t8 asc + s desc: elementwise min = bitonic holding 8 smallest of 16
#pragma unroll
          for (int i = 0; i < 8; ++i) t8[q][i] = fminf(t8[q][i], s[i]);
          bitonic_merge8_asc(t8[q]);
        }
      }
      if (T < 3) {
#pragma unroll
        for (int k = 0; k < 4; ++k) { px[k] = qx[k]; py[k] = qy[k]; pz[k] = qz[k]; }
      }
    }

    // ---- cross-group merge: per row, 16 lists of 8 -> top-16 ----
    __syncthreads();
#pragma unroll
    for (int q = 0; q < 4; ++q) {
      const int rl = q * 16 + r;
#pragma unroll
      for (int i = 0; i < 8; ++i) smem_f[rl * 144 + g * 9 + i] = t8[q][i];
    }
    if (g == 0) {
#pragma unroll
      for (int q = 0; q < 4; ++q) smem_f[AA_OFF + q * 16 + r] = aa4[q];
    }
    __syncthreads();
    // L1: 512 pair-merges (8+8 -> full 16, in place), 2 per thread
#pragma unroll
    for (int w2 = 0; w2 < 2; ++w2) {
      const int id = t + w2 * 256;
      fullmerge8_inplace(&smem_f[(id >> 3) * 144 + (id & 7) * 18]);
    }
    __syncthreads();
    {  // L2: 256 keep-16 merges
      float* A = &smem_f[(t >> 2) * 144 + (t & 3) * 36];
      keep16_lds(A, A + 18);
    }
    __syncthreads();
    if (t < 128) {  // L3: 128 keep-16 merges
      float* A = &smem_f[(t >> 1) * 144 + (t & 1) * 72];
      keep16_lds(A, A + 36);
    }
    __syncthreads();
    if (t < 64) {  // L4 + stats: one row per lane of wave 0
      const float* A = &smem_f[t * 144];
      const float* Bl = A + 72;
      float f[16];
#pragma unroll
      for (int i = 0; i < 16; ++i) f[i] = fminf(A[i], Bl[15 - i]);
      bitonic_merge16_asc(f);
      const float aar = smem_f[AA_OFF + t];
      float d16[16], sum = 0.f;
#pragma unroll
      for (int i = 0; i < 16; ++i) {
        d16[i] = sqrtf(fmaxf(f[i] + aar, 1e-12f));  // self -> 1e-6, rank 0
        sum += d16[i];
      }
      const float mean = sum * 0.0625f;
      float var = 0.f;
#pragma unroll
      for (int i = 0; i < 16; ++i) {
        float e = d16[i] - mean;
        var = fmaf(e, e, var);
      }
      float var_acc = var * (1.f / 15.f);  // unbiased
      float rep_acc = 0.f;
#pragma unroll
      for (int i = 1; i <= 4; ++i) rep_acc += fmaxf(0.01f - d16[i], 0.f);
      const float rs = wave_sum(rep_acc);
      const float vs = wave_sum(var_acc);
      if (t == 0) {
        ws[WS_REP + rid] = rs;
        ws[WS_SMO + rid] = vs;
      }
    }
  } else {
    // ================= min roles: chamfer1 / chamfer2 / coverage =================
    // 128 rows/block, 8 rows/thread: each float4 LDS read feeds 8 rows.
    const int mid = vb - R3_NB;
    int role, rel;
    if (mid < CD_NB)          { role = 0; rel = mid; }
    else if (mid < 2 * CD_NB) { role = 1; rel = mid - CD_NB; }
    else                      { role = 2; rel = mid - 2 * CD_NB; }

    int b, row0;
    if (role == 2) { b = rel >> 4; row0 = (rel & 15) * 128; }  // 16 blocks/batch
    else           { b = rel >> 5; row0 = (rel & 31) * 128; }  // 32 blocks/batch

    const float* colsrc = (role == 0) ? gt : pred;
    const float* rowsrc = (role == 1) ? gt : (role == 2) ? partial : pred;
    const int rpb = (role == 2) ? K_ : N_;
    const size_t cbase = (size_t)b * N_ * 3;

    float nx[8], ny[8], nz[8], aa8[8];
#pragma unroll
    for (int q = 0; q < 8; ++q) {
      const size_t p = ((size_t)b * rpb + row0 + q * 16 + r) * 3;
      const float x = rowsrc[p], y = rowsrc[p + 1], z = rowsrc[p + 2];
      aa8[q] = fmaf(x, x, fmaf(y, y, z * z));
      nx[q] = -2.f * x; ny[q] = -2.f * y; nz[q] = -2.f * z;
    }

    float m[32];  // chain (q, col&3): 32 independent fmin chains
#pragma unroll
    for (int i = 0; i < 32; ++i) m[i] = FLT_MAX;

    float px[4], py[4], pz[4], qx[4], qy[4], qz[4];
#pragma unroll
    for (int k = 0; k < 4; ++k) {
      const size_t p = cbase + 3 * (size_t)(t + k * 256);
      px[k] = colsrc[p]; py[k] = colsrc[p + 1]; pz[k] = colsrc[p + 2];
    }

#pragma unroll 1
    for (int T = 0; T < 4; ++T) {
      __syncthreads();
#pragma unroll
      for (int k = 0; k < 4; ++k) {
        const int i = t + k * 256;
        tile[(i >> 6) * GPAD + (i & 63)] =
            make_float4(px[k], py[k], pz[k],
                        fmaf(px[k], px[k], fmaf(py[k], py[k], pz[k] * pz[k])));
      }
      if (T < 3) {
#pragma unroll
        for (int k = 0; k < 4; ++k) {
          const size_t p = cbase + 3 * (size_t)((T + 1) * 1024 + t + k * 256);
          qx[k] = colsrc[p]; qy[k] = colsrc[p + 1]; qz[k] = colsrc[p + 2];
        }
      }
      __syncthreads();

#pragma unroll 4
      for (int j = 0; j < 64; j += 4) {
        const float4 c0 = tile[base + j + 0];
        const float4 c1 = tile[base + j + 1];
        const float4 c2 = tile[base + j + 2];
        const float4 c3 = tile[base + j + 3];
#pragma unroll
        for (int q = 0; q < 8; ++q) {
          m[q * 4 + 0] = fminf(m[q * 4 + 0], fmaf(nx[q], c0.x, fmaf(ny[q], c0.y, fmaf(nz[q], c0.z, c0.w))));
          m[q * 4 + 1] = fminf(m[q * 4 + 1], fmaf(nx[q], c1.x, fmaf(ny[q], c1.y, fmaf(nz[q], c1.z, c1.w))));
          m[q * 4 + 2] = fminf(m[q * 4 + 2], fmaf(nx[q], c2.x, fmaf(ny[q], c2.y, fmaf(nz[q], c2.z, c2.w))));
          m[q * 4 + 3] = fminf(m[q * 4 + 3], fmaf(nx[q], c3.x, fmaf(ny[q], c3.y, fmaf(nz[q], c3.z, c3.w))));
        }
      }
      if (T < 3) {
#pragma unroll
        for (int k = 0; k < 4; ++k) { px[k] = qx[k]; py[k] = qy[k]; pz[k] = qz[k]; }
      }
    }

    __syncthreads();
#pragma unroll
    for (int q = 0; q < 8; ++q) {
      // +aa[q] is constant per row: commutes with the cross-group min
      const float mm = fminf(fminf(m[q * 4 + 0], m[q * 4 + 1]),
                             fminf(m[q * 4 + 2], m[q * 4 + 3])) + aa8[q];
      smem_f[(q * 16 + r) * 17 + g] = mm;  // stride 17: conflict-free
    }
    __syncthreads();
    if (t < 128) {  // waves 0-1: one row per lane
      float mm = FLT_MAX;
#pragma unroll
      for (int k = 0; k < 16; ++k) mm = fminf(mm, smem_f[t * 17 + k]);
      float d = sqrtf(fmaxf(mm, 1e-12f));
      d = wave_sum(d);
      if ((t & 63) == 0) smem_f[2176 + (t >> 6)] = d;
    }
    __syncthreads();
    if (t == 0) {
      const float S = smem_f[2176] + smem_f[2177];
      const int slot = (role == 0) ? WS_CD1 + rel : (role == 1) ? WS_CD2 + rel : WS_COV + rel;
      ws[slot] = S;
    }
  }
}

__global__ void finalize(const float* __restrict__ ws, float* __restrict__ out) {
  __shared__ float sc[20];
  const int t = threadIdx.x;
  const int offs[5] = {WS_REP, WS_SMO, WS_CD1, WS_CD2, WS_COV};
  const int lens[5] = {256, 256, 128, 128, 64};
  float v[5];
#pragma unroll
  for (int s5 = 0; s5 < 5; ++s5) {
    float s = 0.f;
    for (int i = t; i < lens[s5]; i += TPB) s += ws[offs[s5] + i];
    v[s5] = wave_sum(s);
  }
  if ((t & 63) == 0) {
#pragma unroll
    for (int s5 = 0; s5 < 5; ++s5) sc[s5 * 4 + (t >> 6)] = v[s5];
  }
  __syncthreads();
  if (t == 0) {
    float S[5];
#pragma unroll
    for (int s5 = 0; s5 < 5; ++s5)
      S[s5] = sc[s5 * 4] + sc[s5 * 4 + 1] + sc[s5 * 4 + 2] + sc[s5 * 4 + 3];
    const float rep    = S[0] / (float)(B_ * N_ * 4);
    const float smooth = S[1] / (float)(B_ * N_);
    const float cd     = (S[2] + S[3]) / (float)(B_ * N_);
    const float cov    = S[4] / (float)(B_ * K_);
    const float total  = 1.0f * cd + 0.01f * rep + 0.005f * smooth + 0.1f * cov;
    out[0] = total;
    out[1] = cd;
    out[2] = rep;
    out[3] = smooth;
    out[4] = cov;
  }
}

extern "C" void kernel_launch(void* const* d_in, const int* in_sizes, int n_in,
                              void* d_out, int out_size, void* d_ws, size_t ws_size,
                              hipStream_t stream) {
  const float* pred    = (const float*)d_in[0];  // [4,4096,3]
  const float* gt      = (const float*)d_in[1];  // [4,4096,3]
  const float* partial = (const float*)d_in[2];  // [4,2048,3]
  float* out = (float*)d_out;                    // 5 scalars
  float* ws  = (float*)d_ws;                     // >= 832 floats, all written each call

  fused_loss<<<GRID, TPB, 0, stream>>>(pred, gt, partial, ws);
  finalize<<<1, TPB, 0, stream>>>(ws, out);
}

// Round 2
// 106.375 us; speedup vs baseline: 1.0129x; 1.0129x over previous
//
#include <hip/hip_runtime.h>
#include <float.h>
#include <math.h>

// Problem constants (from reference setup_inputs)
#define B_ 4
#define N_ 4096
#define K_ 2048
#define TPB 256

// R9 structure: register-blocked rows (R8's per-pair LDS win) at full grid
// residency (R7's parallelism). R8 failed on grid=576 -> 14% occupancy.
//   role-3: 2 rows/thread, 32 rows/block, 512 blocks   (8 B LDS per pair)
//   chamfer: 8 rows/thread, 64 rows/block, 256 blocks/direction (2 B/pair)
//   coverage: 8 rows/thread, 64 rows/block, 128 blocks
// grid = 1152 = 4.5 blocks/CU, fully resident (LDS 18.6 KB -> 8 blocks/CU).
#define R3_NB 512
#define CD_NB 256
#define COV_NB 128
#define GRID (R3_NB + 2 * CD_NB + COV_NB)  // 1152

// ws partial-sum layout (floats); every slot written every call -> no zeroing
#define WS_REP 0      // 512
#define WS_SMO 512    // 512
#define WS_CD1 1024   // 256
#define WS_CD2 1280   // 256
#define WS_COV 1536   // 128

// role-3 tile: 16 groups x 65 float4 (16-lane broadcast, disjoint 4-bank
// ranges per wave). min tile: 32 groups x 33 float4 (8-lane broadcast,
// banks 4g mod 32 -> disjoint ranges, conflict-free).
#define GPAD3 65
#define GPADM 33
// role-3 merge area: 32 rows x 16 lists; 8-lists at stride 9, L1 merges pairs
// in place to 16-lists at stride 18. 32*144 = 4608, + 32 aa = 4640 floats.
#define AA_OFF 4608
#define SMEM_F 4640   // 18560 B

__device__ inline float wave_sum(float v) {
#pragma unroll
  for (int off = 32; off > 0; off >>= 1) v += __shfl_down(v, off, 64);
  return v;
}

__device__ inline void ce_asc(float& a, float& b) {
  float lo = fminf(a, b), hi = fmaxf(a, b);
  a = lo; b = hi;
}
__device__ inline void ce_desc(float& a, float& b) {
  float lo = fminf(a, b), hi = fmaxf(a, b);
  a = hi; b = lo;
}

// Batcher odd-even mergesort of 8, DESCENDING: 19 CEs (validated R6)
__device__ inline void bsort8_desc(float (&v)[8]) {
#define CE(i, j) ce_desc(v[i], v[j])
  CE(0,1); CE(2,3); CE(4,5); CE(6,7);
  CE(0,2); CE(1,3); CE(4,6); CE(5,7);
  CE(1,2); CE(5,6);
  CE(0,4); CE(1,5); CE(2,6); CE(3,7);
  CE(2,4); CE(3,5);
  CE(1,2); CE(3,4); CE(5,6);
#undef CE
}

// bitonic 8-sequence cleanup to ascending (3 stages, 12 CEs)
__device__ inline void bitonic_merge8_asc(float (&v)[8]) {
#pragma unroll
  for (int j = 4; j > 0; j >>= 1) {
#pragma unroll
    for (int i = 0; i < 8; ++i) {
      int ixj = i ^ j;
      if (ixj > i) ce_asc(v[i], v[ixj]);
    }
  }
}

// bitonic 16-sequence cleanup to ascending (4 stages, 32 CEs)
__device__ inline void bitonic_merge16_asc(float (&v)[16]) {
#pragma unroll
  for (int j = 8; j > 0; j >>= 1) {
#pragma unroll
    for (int i = 0; i < 16; ++i) {
      int ixj = i ^ j;
      if (ixj > i) ce_asc(v[i], v[ixj]);
    }
  }
}

// L1: two ascending 8-lists at A[0..7] and A[9..16] -> full ascending 16 at
// A[0..15] (in place; task region is 18 floats, reads complete before writes).
__device__ inline void fullmerge8_inplace(float* A) {
  float m[16];
#pragma unroll
  for (int i = 0; i < 8; ++i) m[i] = A[i];
#pragma unroll
  for (int i = 0; i < 8; ++i) m[8 + i] = A[9 + 7 - i];  // asc then desc = bitonic
  bitonic_merge16_asc(m);
#pragma unroll
  for (int i = 0; i < 16; ++i) A[i] = m[i];
}

// merge two ascending-16 lists -> 16 smallest ascending, stored to A
__device__ inline void keep16_lds(float* A, const float* Bl) {
  float m[16];
#pragma unroll
  for (int i = 0; i < 16; ++i) m[i] = fminf(A[i], Bl[15 - i]);
  bitonic_merge16_asc(m);
#pragma unroll
  for (int i = 0; i < 16; ++i) A[i] = m[i];
}

// Distances via s' = |c|^2 - 2 a.c (LDS tile stores (x,y,z,|c|^2));
// |a|^2 added back after selection (monotone shift). Validated since R3.
// Role-3 keeps per-thread top-8 over 256 cands (16 threads/row): row top-8
// provably exact; ranks 9-16 exact unless one thread holds >=9 of the row's
// top-16 (P~3e-6/row, error ~1e-7 if fired). Unchanged since R7.
__global__ __launch_bounds__(TPB, 4) void fused_loss(const float* __restrict__ pred,
                                                     const float* __restrict__ gt,
                                                     const float* __restrict__ partial,
                                                     float* __restrict__ ws) {
  // union: r3 tile (16*65 f4 = 4160 f) / r3 merge lists (4640 f)
  // / min tile (32*33 f4 = 4224 f) / min reduce area (64*33 = 2112 f)
  __shared__ __align__(16) float smem_f[SMEM_F];
  float4* tile = reinterpret_cast<float4*>(smem_f);

  const int blk = blockIdx.x;
  const int t = threadIdx.x;

  if (blk < R3_NB) {
    // ================= role 3: pred self top-16 =================
    // 32 rows/block, 2 rows/thread; each float4 LDS read feeds 2 rows.
    const int r = t & 15;        // row slot
    const int g = t >> 4;        // column group (16 groups x 64 cols)
    const int base = g * GPAD3;
    const int rid = blk;
    const int b = rid >> 7;              // 128 blocks/batch
    const int row0 = (rid & 127) * 32;
    const size_t cbase = (size_t)b * N_ * 3;

    float nx[2], ny[2], nz[2], aa2[2];
#pragma unroll
    for (int q = 0; q < 2; ++q) {
      const size_t p = cbase + (size_t)(row0 + q * 16 + r) * 3;
      const float x = pred[p], y = pred[p + 1], z = pred[p + 2];
      aa2[q] = fmaf(x, x, fmaf(y, y, z * z));
      nx[q] = -2.f * x; ny[q] = -2.f * y; nz[q] = -2.f * z;
    }

    float t8[2][8];
#pragma unroll
    for (int q = 0; q < 2; ++q)
#pragma unroll
      for (int i = 0; i < 8; ++i) t8[q][i] = FLT_MAX;

    // T14 prefetch: next tile's 4 points live in regs while current computes.
    float px[4], py[4], pz[4], qx[4], qy[4], qz[4];
#pragma unroll
    for (int k = 0; k < 4; ++k) {
      const size_t p = cbase + 3 * (size_t)(t + k * 256);
      px[k] = pred[p]; py[k] = pred[p + 1]; pz[k] = pred[p + 2];
    }

#pragma unroll 1
    for (int T = 0; T < 4; ++T) {
      __syncthreads();
#pragma unroll
      for (int k = 0; k < 4; ++k) {
        const int i = t + k * 256;
        tile[(i >> 6) * GPAD3 + (i & 63)] =
            make_float4(px[k], py[k], pz[k],
                        fmaf(px[k], px[k], fmaf(py[k], py[k], pz[k] * pz[k])));
      }
      if (T < 3) {  // issue next-tile loads; latency hides under compute
#pragma unroll
        for (int k = 0; k < 4; ++k) {
          const size_t p = cbase + 3 * (size_t)((T + 1) * 1024 + t + k * 256);
          qx[k] = pred[p]; qy[k] = pred[p + 1]; qz[k] = pred[p + 2];
        }
      }
      __syncthreads();

#pragma unroll 1
      for (int jb = 0; jb < 64; jb += 8) {
        float4 c[8];
#pragma unroll
        for (int u = 0; u < 8; ++u) c[u] = tile[base + jb + u];
#pragma unroll
        for (int q = 0; q < 2; ++q) {
          float s[8];
#pragma unroll
          for (int u = 0; u < 8; ++u)
            s[u] = fmaf(nx[q], c[u].x, fmaf(ny[q], c[u].y, fmaf(nz[q], c[u].z, c[u].w)));
          bsort8_desc(s);
          // t8 asc + s desc: elementwise min = bitonic holding 8 smallest of 16
#pragma unroll
          for (int i = 0; i < 8; ++i) t8[q][i] = fminf(t8[q][i], s[i]);
          bitonic_merge8_asc(t8[q]);
        }
      }
      if (T < 3) {
#pragma unroll
        for (int k = 0; k < 4; ++k) { px[k] = qx[k]; py[k] = qy[k]; pz[k] = qz[k]; }
      }
    }

    // ---- cross-group merge: per row, 16 lists of 8 -> top-16 ----
    __syncthreads();
#pragma unroll
    for (int q = 0; q < 2; ++q) {
      const int rl = q * 16 + r;
#pragma unroll
      for (int i = 0; i < 8; ++i) smem_f[rl * 144 + g * 9 + i] = t8[q][i];
    }
    if (g == 0) {
#pragma unroll
      for (int q = 0; q < 2; ++q) smem_f[AA_OFF + q * 16 + r] = aa2[q];
    }
    __syncthreads();
    // L1: 256 pair-merges (8+8 -> full 16, in place), 1 per thread
    fullmerge8_inplace(&smem_f[(t >> 3) * 144 + (t & 7) * 18]);
    __syncthreads();
    if (t < 128) {  // L2: 128 keep-16 merges
      float* A = &smem_f[(t >> 2) * 144 + (t & 3) * 36];
      keep16_lds(A, A + 18);
    }
    __syncthreads();
    if (t < 64) {  // L3: 64 keep-16 merges
      float* A = &smem_f[(t >> 1) * 144 + (t & 1) * 72];
      keep16_lds(A, A + 36);
    }
    __syncthreads();
    if (t < 64) {  // L4 + stats: 32 rows on wave 0 (lanes 32-63 contribute 0)
      float rep_acc = 0.f, var_acc = 0.f;
      if (t < 32) {
        const float* A = &smem_f[t * 144];
        const float* Bl = A + 72;
        float f[16];
#pragma unroll
        for (int i = 0; i < 16; ++i) f[i] = fminf(A[i], Bl[15 - i]);
        bitonic_merge16_asc(f);
        const float aar = smem_f[AA_OFF + t];
        float d16[16], sum = 0.f;
#pragma unroll
        for (int i = 0; i < 16; ++i) {
          d16[i] = sqrtf(fmaxf(f[i] + aar, 1e-12f));  // self -> 1e-6, rank 0
          sum += d16[i];
        }
        const float mean = sum * 0.0625f;
        float var = 0.f;
#pragma unroll
        for (int i = 0; i < 16; ++i) {
          float e = d16[i] - mean;
          var = fmaf(e, e, var);
        }
        var_acc = var * (1.f / 15.f);  // unbiased
#pragma unroll
        for (int i = 1; i <= 4; ++i) rep_acc += fmaxf(0.01f - d16[i], 0.f);
      }
      const float rs = wave_sum(rep_acc);
      const float vs = wave_sum(var_acc);
      if (t == 0) {
        ws[WS_REP + rid] = rs;
        ws[WS_SMO + rid] = vs;
      }
    }
  } else {
    // ================= min roles: chamfer1 / chamfer2 / coverage =================
    // 64 rows/block, 8 rows/thread: each float4 LDS read feeds 8 rows.
    const int mid = blk - R3_NB;
    int role, rel;
    if (mid < CD_NB)          { role = 0; rel = mid; }
    else if (mid < 2 * CD_NB) { role = 1; rel = mid - CD_NB; }
    else                      { role = 2; rel = mid - 2 * CD_NB; }

    const int r = t & 7;         // row slot (8)
    const int g = t >> 3;        // column group (32 groups x 32 cols)
    const int base = g * GPADM;

    int b, row0;
    if (role == 2) { b = rel >> 5; row0 = (rel & 31) * 64; }  // 32 blocks/batch
    else           { b = rel >> 6; row0 = (rel & 63) * 64; }  // 64 blocks/batch

    const float* colsrc = (role == 0) ? gt : pred;
    const float* rowsrc = (role == 1) ? gt : (role == 2) ? partial : pred;
    const int rpb = (role == 2) ? K_ : N_;
    const size_t cbase = (size_t)b * N_ * 3;

    float nx[8], ny[8], nz[8], aa8[8];
#pragma unroll
    for (int q = 0; q < 8; ++q) {
      const size_t p = ((size_t)b * rpb + row0 + q * 8 + r) * 3;
      const float x = rowsrc[p], y = rowsrc[p + 1], z = rowsrc[p + 2];
      aa8[q] = fmaf(x, x, fmaf(y, y, z * z));
      nx[q] = -2.f * x; ny[q] = -2.f * y; nz[q] = -2.f * z;
    }

    float m[32];  // chain (q, col&3): 32 independent fmin chains
#pragma unroll
    for (int i = 0; i < 32; ++i) m[i] = FLT_MAX;

    float px[4], py[4], pz[4], qx[4], qy[4], qz[4];
#pragma unroll
    for (int k = 0; k < 4; ++k) {
      const size_t p = cbase + 3 * (size_t)(t + k * 256);
      px[k] = colsrc[p]; py[k] = colsrc[p + 1]; pz[k] = colsrc[p + 2];
    }

#pragma unroll 1
    for (int T = 0; T < 4; ++T) {
      __syncthreads();
#pragma unroll
      for (int k = 0; k < 4; ++k) {
        const int i = t + k * 256;
        tile[(i >> 5) * GPADM + (i & 31)] =
            make_float4(px[k], py[k], pz[k],
                        fmaf(px[k], px[k], fmaf(py[k], py[k], pz[k] * pz[k])));
      }
      if (T < 3) {
#pragma unroll
        for (int k = 0; k < 4; ++k) {
          const size_t p = cbase + 3 * (size_t)((T + 1) * 1024 + t + k * 256);
          qx[k] = colsrc[p]; qy[k] = colsrc[p + 1]; qz[k] = colsrc[p + 2];
        }
      }
      __syncthreads();

#pragma unroll 4
      for (int j = 0; j < 32; j += 4) {
        const float4 c0 = tile[base + j + 0];
        const float4 c1 = tile[base + j + 1];
        const float4 c2 = tile[base + j + 2];
        const float4 c3 = tile[base + j + 3];
#pragma unroll
        for (int q = 0; q < 8; ++q) {
          m[q * 4 + 0] = fminf(m[q * 4 + 0], fmaf(nx[q], c0.x, fmaf(ny[q], c0.y, fmaf(nz[q], c0.z, c0.w))));
          m[q * 4 + 1] = fminf(m[q * 4 + 1], fmaf(nx[q], c1.x, fmaf(ny[q], c1.y, fmaf(nz[q], c1.z, c1.w))));
          m[q * 4 + 2] = fminf(m[q * 4 + 2], fmaf(nx[q], c2.x, fmaf(ny[q], c2.y, fmaf(nz[q], c2.z, c2.w))));
          m[q * 4 + 3] = fminf(m[q * 4 + 3], fmaf(nx[q], c3.x, fmaf(ny[q], c3.y, fmaf(nz[q], c3.z, c3.w))));
        }
      }
      if (T < 3) {
#pragma unroll
        for (int k = 0; k < 4; ++k) { px[k] = qx[k]; py[k] = qy[k]; pz[k] = qz[k]; }
      }
    }

    __syncthreads();
#pragma unroll
    for (int q = 0; q < 8; ++q) {
      // +aa[q] is constant per row: commutes with the cross-group min
      const float mm = fminf(fminf(m[q * 4 + 0], m[q * 4 + 1]),
                             fminf(m[q * 4 + 2], m[q * 4 + 3])) + aa8[q];
      smem_f[(q * 8 + r) * GPADM + g] = mm;  // stride 33: reads 2-way (free)
    }
    __syncthreads();
    if (t < 64) {  // wave 0: one row per lane
      float mm = FLT_MAX;
#pragma unroll
      for (int k = 0; k < 32; ++k) mm = fminf(mm, smem_f[t * GPADM + k]);
      float d = sqrtf(fmaxf(mm, 1e-12f));
      d = wave_sum(d);
      if (t == 0) {
        const int slot = (role == 0) ? WS_CD1 + rel : (role == 1) ? WS_CD2 + rel : WS_COV + rel;
        ws[slot] = d;
      }
    }
  }
}

__global__ void finalize(const float* __restrict__ ws, float* __restrict__ out) {
  __shared__ float sc[20];
  const int t = threadIdx.x;
  const int offs[5] = {WS_REP, WS_SMO, WS_CD1, WS_CD2, WS_COV};
  const int lens[5] = {512, 512, 256, 256, 128};
  float v[5];
#pragma unroll
  for (int s5 = 0; s5 < 5; ++s5) {
    float s = 0.f;
    for (int i = t; i < lens[s5]; i += TPB) s += ws[offs[s5] + i];
    v[s5] = wave_sum(s);
  }
  if ((t & 63) == 0) {
#pragma unroll
    for (int s5 = 0; s5 < 5; ++s5) sc[s5 * 4 + (t >> 6)] = v[s5];
  }
  __syncthreads();
  if (t == 0) {
    float S[5];
#pragma unroll
    for (int s5 = 0; s5 < 5; ++s5)
      S[s5] = sc[s5 * 4] + sc[s5 * 4 + 1] + sc[s5 * 4 + 2] + sc[s5 * 4 + 3];
    const float rep    = S[0] / (float)(B_ * N_ * 4);
    const float smooth = S[1] / (float)(B_ * N_);
    const float cd     = (S[2] + S[3]) / (float)(B_ * N_);
    const float cov    = S[4] / (float)(B_ * K_);
    const float total  = 1.0f * cd + 0.01f * rep + 0.005f * smooth + 0.1f * cov;
    out[0] = total;
    out[1] = cd;
    out[2] = rep;
    out[3] = smooth;
    out[4] = cov;
  }
}

extern "C" void kernel_launch(void* const* d_in, const int* in_sizes, int n_in,
                              void* d_out, int out_size, void* d_ws, size_t ws_size,
                              hipStream_t stream) {
  const float* pred    = (const float*)d_in[0];  // [4,4096,3]
  const float* gt      = (const float*)d_in[1];  // [4,4096,3]
  const float* partial = (const float*)d_in[2];  // [4,2048,3]
  float* out = (float*)d_out;                    // 5 scalars
  float* ws  = (float*)d_ws;                     // >= 1664 floats, all written each call

  fused_loss<<<GRID, TPB, 0, stream>>>(pred, gt, partial, ws);
  finalize<<<1, TPB, 0, stream>>>(ws, out);
}

// Round 3
// 97.550 us; speedup vs baseline: 1.1045x; 1.0905x over previous
//
#include <hip/hip_runtime.h>
#include <float.h>
#include <math.h>

// Problem constants (from reference setup_inputs)
#define B_ 4
#define N_ 4096
#define K_ 2048
#define TPB 256

// R10 = R9 structure with the spill fixed. R9's launch_bounds(256,4) capped
// VGPRs at 128 vs ~130+ demand -> 21.9 MB scratch writes/dispatch (vs 6.6 KB
// of real output). (256,3) raises the cap to ~170: R8 measured 84 VGPR
// no-spill on the same min-path register demand.
//   role-3: 2 rows/thread, 32 rows/block, 512 blocks   (8 B LDS per pair)
//   chamfer: 8 rows/thread, 64 rows/block, 256 blocks/direction (2 B/pair)
//   coverage: 8 rows/thread, 64 rows/block, 128 blocks
// grid = 1152 = 4.5 blocks/CU; VGPR-limited occupancy ~5-6 blocks/CU -> resident.
#define R3_NB 512
#define CD_NB 256
#define COV_NB 128
#define GRID (R3_NB + 2 * CD_NB + COV_NB)  // 1152

// ws partial-sum layout (floats); every slot written every call -> no zeroing
#define WS_REP 0      // 512
#define WS_SMO 512    // 512
#define WS_CD1 1024   // 256
#define WS_CD2 1280   // 256
#define WS_COV 1536   // 128

// role-3 tile: 16 groups x 65 float4 (16-lane broadcast, disjoint 4-bank
// ranges per wave). min tile: 32 groups x 33 float4 (8-lane broadcast,
// banks 4g mod 32 -> disjoint ranges, conflict-free).
#define GPAD3 65
#define GPADM 33
// role-3 merge area: 32 rows x 16 lists; 8-lists at stride 9, L1 merges pairs
// in place to 16-lists at stride 18. 32*144 = 4608, + 32 aa = 4640 floats.
#define AA_OFF 4608
#define SMEM_F 4640   // 18560 B

__device__ inline float wave_sum(float v) {
#pragma unroll
  for (int off = 32; off > 0; off >>= 1) v += __shfl_down(v, off, 64);
  return v;
}

__device__ inline void ce_asc(float& a, float& b) {
  float lo = fminf(a, b), hi = fmaxf(a, b);
  a = lo; b = hi;
}
__device__ inline void ce_desc(float& a, float& b) {
  float lo = fminf(a, b), hi = fmaxf(a, b);
  a = hi; b = lo;
}

// Batcher odd-even mergesort of 8, DESCENDING: 19 CEs (validated R6)
__device__ inline void bsort8_desc(float (&v)[8]) {
#define CE(i, j) ce_desc(v[i], v[j])
  CE(0,1); CE(2,3); CE(4,5); CE(6,7);
  CE(0,2); CE(1,3); CE(4,6); CE(5,7);
  CE(1,2); CE(5,6);
  CE(0,4); CE(1,5); CE(2,6); CE(3,7);
  CE(2,4); CE(3,5);
  CE(1,2); CE(3,4); CE(5,6);
#undef CE
}

// bitonic 8-sequence cleanup to ascending (3 stages, 12 CEs)
__device__ inline void bitonic_merge8_asc(float (&v)[8]) {
#pragma unroll
  for (int j = 4; j > 0; j >>= 1) {
#pragma unroll
    for (int i = 0; i < 8; ++i) {
      int ixj = i ^ j;
      if (ixj > i) ce_asc(v[i], v[ixj]);
    }
  }
}

// bitonic 16-sequence cleanup to ascending (4 stages, 32 CEs)
__device__ inline void bitonic_merge16_asc(float (&v)[16]) {
#pragma unroll
  for (int j = 8; j > 0; j >>= 1) {
#pragma unroll
    for (int i = 0; i < 16; ++i) {
      int ixj = i ^ j;
      if (ixj > i) ce_asc(v[i], v[ixj]);
    }
  }
}

// L1: two ascending 8-lists at A[0..7] and A[9..16] -> full ascending 16 at
// A[0..15] (in place; task region is 18 floats, reads complete before writes).
__device__ inline void fullmerge8_inplace(float* A) {
  float m[16];
#pragma unroll
  for (int i = 0; i < 8; ++i) m[i] = A[i];
#pragma unroll
  for (int i = 0; i < 8; ++i) m[8 + i] = A[9 + 7 - i];  // asc then desc = bitonic
  bitonic_merge16_asc(m);
#pragma unroll
  for (int i = 0; i < 16; ++i) A[i] = m[i];
}

// merge two ascending-16 lists -> 16 smallest ascending, stored to A
__device__ inline void keep16_lds(float* A, const float* Bl) {
  float m[16];
#pragma unroll
  for (int i = 0; i < 16; ++i) m[i] = fminf(A[i], Bl[15 - i]);
  bitonic_merge16_asc(m);
#pragma unroll
  for (int i = 0; i < 16; ++i) A[i] = m[i];
}

// Distances via s' = |c|^2 - 2 a.c (LDS tile stores (x,y,z,|c|^2));
// |a|^2 added back after selection (monotone shift). Validated since R3.
// Role-3 keeps per-thread top-8 over 256 cands (16 threads/row): row top-8
// provably exact; ranks 9-16 exact unless one thread holds >=9 of the row's
// top-16 (P~3e-6/row, error ~1e-7 if fired). Unchanged since R7.
__global__ __launch_bounds__(TPB, 3) void fused_loss(const float* __restrict__ pred,
                                                     const float* __restrict__ gt,
                                                     const float* __restrict__ partial,
                                                     float* __restrict__ ws) {
  // union: r3 tile (16*65 f4 = 4160 f) / r3 merge lists (4640 f)
  // / min tile (32*33 f4 = 4224 f) / min reduce area (64*33 = 2112 f)
  __shared__ __align__(16) float smem_f[SMEM_F];
  float4* tile = reinterpret_cast<float4*>(smem_f);

  const int blk = blockIdx.x;
  const int t = threadIdx.x;

  if (blk < R3_NB) {
    // ================= role 3: pred self top-16 =================
    // 32 rows/block, 2 rows/thread; each float4 LDS read feeds 2 rows.
    const int r = t & 15;        // row slot
    const int g = t >> 4;        // column group (16 groups x 64 cols)
    const int base = g * GPAD3;
    const int rid = blk;
    const int b = rid >> 7;              // 128 blocks/batch
    const int row0 = (rid & 127) * 32;
    const size_t cbase = (size_t)b * N_ * 3;

    float nx[2], ny[2], nz[2], aa2[2];
#pragma unroll
    for (int q = 0; q < 2; ++q) {
      const size_t p = cbase + (size_t)(row0 + q * 16 + r) * 3;
      const float x = pred[p], y = pred[p + 1], z = pred[p + 2];
      aa2[q] = fmaf(x, x, fmaf(y, y, z * z));
      nx[q] = -2.f * x; ny[q] = -2.f * y; nz[q] = -2.f * z;
    }

    float t8[2][8];
#pragma unroll
    for (int q = 0; q < 2; ++q)
#pragma unroll
      for (int i = 0; i < 8; ++i) t8[q][i] = FLT_MAX;

    // T14 prefetch: next tile's 4 points live in regs while current computes.
    float px[4], py[4], pz[4], qx[4], qy[4], qz[4];
#pragma unroll
    for (int k = 0; k < 4; ++k) {
      const size_t p = cbase + 3 * (size_t)(t + k * 256);
      px[k] = pred[p]; py[k] = pred[p + 1]; pz[k] = pred[p + 2];
    }

#pragma unroll 1
    for (int T = 0; T < 4; ++T) {
      __syncthreads();
#pragma unroll
      for (int k = 0; k < 4; ++k) {
        const int i = t + k * 256;
        tile[(i >> 6) * GPAD3 + (i & 63)] =
            make_float4(px[k], py[k], pz[k],
                        fmaf(px[k], px[k], fmaf(py[k], py[k], pz[k] * pz[k])));
      }
      if (T < 3) {  // issue next-tile loads; latency hides under compute
#pragma unroll
        for (int k = 0; k < 4; ++k) {
          const size_t p = cbase + 3 * (size_t)((T + 1) * 1024 + t + k * 256);
          qx[k] = pred[p]; qy[k] = pred[p + 1]; qz[k] = pred[p + 2];
        }
      }
      __syncthreads();

#pragma unroll 1
      for (int jb = 0; jb < 64; jb += 8) {
        float4 c[8];
#pragma unroll
        for (int u = 0; u < 8; ++u) c[u] = tile[base + jb + u];
#pragma unroll
        for (int q = 0; q < 2; ++q) {
          float s[8];
#pragma unroll
          for (int u = 0; u < 8; ++u)
            s[u] = fmaf(nx[q], c[u].x, fmaf(ny[q], c[u].y, fmaf(nz[q], c[u].z, c[u].w)));
          bsort8_desc(s);
          // t8 asc + s desc: elementwise min = bitonic holding 8 smallest of 16
#pragma unroll
          for (int i = 0; i < 8; ++i) t8[q][i] = fminf(t8[q][i], s[i]);
          bitonic_merge8_asc(t8[q]);
        }
      }
      if (T < 3) {
#pragma unroll
        for (int k = 0; k < 4; ++k) { px[k] = qx[k]; py[k] = qy[k]; pz[k] = qz[k]; }
      }
    }

    // ---- cross-group merge: per row, 16 lists of 8 -> top-16 ----
    __syncthreads();
#pragma unroll
    for (int q = 0; q < 2; ++q) {
      const int rl = q * 16 + r;
#pragma unroll
      for (int i = 0; i < 8; ++i) smem_f[rl * 144 + g * 9 + i] = t8[q][i];
    }
    if (g == 0) {
#pragma unroll
      for (int q = 0; q < 2; ++q) smem_f[AA_OFF + q * 16 + r] = aa2[q];
    }
    __syncthreads();
    // L1: 256 pair-merges (8+8 -> full 16, in place), 1 per thread
    fullmerge8_inplace(&smem_f[(t >> 3) * 144 + (t & 7) * 18]);
    __syncthreads();
    if (t < 128) {  // L2: 128 keep-16 merges
      float* A = &smem_f[(t >> 2) * 144 + (t & 3) * 36];
      keep16_lds(A, A + 18);
    }
    __syncthreads();
    if (t < 64) {  // L3: 64 keep-16 merges
      float* A = &smem_f[(t >> 1) * 144 + (t & 1) * 72];
      keep16_lds(A, A + 36);
    }
    __syncthreads();
    if (t < 64) {  // L4 + stats: 32 rows on wave 0 (lanes 32-63 contribute 0)
      float rep_acc = 0.f, var_acc = 0.f;
      if (t < 32) {
        const float* A = &smem_f[t * 144];
        const float* Bl = A + 72;
        float f[16];
#pragma unroll
        for (int i = 0; i < 16; ++i) f[i] = fminf(A[i], Bl[15 - i]);
        bitonic_merge16_asc(f);
        const float aar = smem_f[AA_OFF + t];
        float d16[16], sum = 0.f;
#pragma unroll
        for (int i = 0; i < 16; ++i) {
          d16[i] = sqrtf(fmaxf(f[i] + aar, 1e-12f));  // self -> 1e-6, rank 0
          sum += d16[i];
        }
        const float mean = sum * 0.0625f;
        float var = 0.f;
#pragma unroll
        for (int i = 0; i < 16; ++i) {
          float e = d16[i] - mean;
          var = fmaf(e, e, var);
        }
        var_acc = var * (1.f / 15.f);  // unbiased
#pragma unroll
        for (int i = 1; i <= 4; ++i) rep_acc += fmaxf(0.01f - d16[i], 0.f);
      }
      const float rs = wave_sum(rep_acc);
      const float vs = wave_sum(var_acc);
      if (t == 0) {
        ws[WS_REP + rid] = rs;
        ws[WS_SMO + rid] = vs;
      }
    }
  } else {
    // ================= min roles: chamfer1 / chamfer2 / coverage =================
    // 64 rows/block, 8 rows/thread: each float4 LDS read feeds 8 rows.
    const int mid = blk - R3_NB;
    int role, rel;
    if (mid < CD_NB)          { role = 0; rel = mid; }
    else if (mid < 2 * CD_NB) { role = 1; rel = mid - CD_NB; }
    else                      { role = 2; rel = mid - 2 * CD_NB; }

    const int r = t & 7;         // row slot (8)
    const int g = t >> 3;        // column group (32 groups x 32 cols)
    const int base = g * GPADM;

    int b, row0;
    if (role == 2) { b = rel >> 5; row0 = (rel & 31) * 64; }  // 32 blocks/batch
    else           { b = rel >> 6; row0 = (rel & 63) * 64; }  // 64 blocks/batch

    const float* colsrc = (role == 0) ? gt : pred;
    const float* rowsrc = (role == 1) ? gt : (role == 2) ? partial : pred;
    const int rpb = (role == 2) ? K_ : N_;
    const size_t cbase = (size_t)b * N_ * 3;

    float nx[8], ny[8], nz[8], aa8[8];
#pragma unroll
    for (int q = 0; q < 8; ++q) {
      const size_t p = ((size_t)b * rpb + row0 + q * 8 + r) * 3;
      const float x = rowsrc[p], y = rowsrc[p + 1], z = rowsrc[p + 2];
      aa8[q] = fmaf(x, x, fmaf(y, y, z * z));
      nx[q] = -2.f * x; ny[q] = -2.f * y; nz[q] = -2.f * z;
    }

    float m[32];  // chain (q, col&3): 32 independent fmin chains
#pragma unroll
    for (int i = 0; i < 32; ++i) m[i] = FLT_MAX;

    float px[4], py[4], pz[4], qx[4], qy[4], qz[4];
#pragma unroll
    for (int k = 0; k < 4; ++k) {
      const size_t p = cbase + 3 * (size_t)(t + k * 256);
      px[k] = colsrc[p]; py[k] = colsrc[p + 1]; pz[k] = colsrc[p + 2];
    }

#pragma unroll 1
    for (int T = 0; T < 4; ++T) {
      __syncthreads();
#pragma unroll
      for (int k = 0; k < 4; ++k) {
        const int i = t + k * 256;
        tile[(i >> 5) * GPADM + (i & 31)] =
            make_float4(px[k], py[k], pz[k],
                        fmaf(px[k], px[k], fmaf(py[k], py[k], pz[k] * pz[k])));
      }
      if (T < 3) {
#pragma unroll
        for (int k = 0; k < 4; ++k) {
          const size_t p = cbase + 3 * (size_t)((T + 1) * 1024 + t + k * 256);
          qx[k] = colsrc[p]; qy[k] = colsrc[p + 1]; qz[k] = colsrc[p + 2];
        }
      }
      __syncthreads();

#pragma unroll 4
      for (int j = 0; j < 32; j += 4) {
        const float4 c0 = tile[base + j + 0];
        const float4 c1 = tile[base + j + 1];
        const float4 c2 = tile[base + j + 2];
        const float4 c3 = tile[base + j + 3];
#pragma unroll
        for (int q = 0; q < 8; ++q) {
          m[q * 4 + 0] = fminf(m[q * 4 + 0], fmaf(nx[q], c0.x, fmaf(ny[q], c0.y, fmaf(nz[q], c0.z, c0.w))));
          m[q * 4 + 1] = fminf(m[q * 4 + 1], fmaf(nx[q], c1.x, fmaf(ny[q], c1.y, fmaf(nz[q], c1.z, c1.w))));
          m[q * 4 + 2] = fminf(m[q * 4 + 2], fmaf(nx[q], c2.x, fmaf(ny[q], c2.y, fmaf(nz[q], c2.z, c2.w))));
          m[q * 4 + 3] = fminf(m[q * 4 + 3], fmaf(nx[q], c3.x, fmaf(ny[q], c3.y, fmaf(nz[q], c3.z, c3.w))));
        }
      }
      if (T < 3) {
#pragma unroll
        for (int k = 0; k < 4; ++k) { px[k] = qx[k]; py[k] = qy[k]; pz[k] = qz[k]; }
      }
    }

    __syncthreads();
#pragma unroll
    for (int q = 0; q < 8; ++q) {
      // +aa[q] is constant per row: commutes with the cross-group min
      const float mm = fminf(fminf(m[q * 4 + 0], m[q * 4 + 1]),
                             fminf(m[q * 4 + 2], m[q * 4 + 3])) + aa8[q];
      smem_f[(q * 8 + r) * GPADM + g] = mm;  // stride 33: reads 2-way (free)
    }
    __syncthreads();
    if (t < 64) {  // wave 0: one row per lane
      float mm = FLT_MAX;
#pragma unroll
      for (int k = 0; k < 32; ++k) mm = fminf(mm, smem_f[t * GPADM + k]);
      float d = sqrtf(fmaxf(mm, 1e-12f));
      d = wave_sum(d);
      if (t == 0) {
        const int slot = (role == 0) ? WS_CD1 + rel : (role == 1) ? WS_CD2 + rel : WS_COV + rel;
        ws[slot] = d;
      }
    }
  }
}

__global__ void finalize(const float* __restrict__ ws, float* __restrict__ out) {
  __shared__ float sc[20];
  const int t = threadIdx.x;
  const int offs[5] = {WS_REP, WS_SMO, WS_CD1, WS_CD2, WS_COV};
  const int lens[5] = {512, 512, 256, 256, 128};
  float v[5];
#pragma unroll
  for (int s5 = 0; s5 < 5; ++s5) {
    float s = 0.f;
    for (int i = t; i < lens[s5]; i += TPB) s += ws[offs[s5] + i];
    v[s5] = wave_sum(s);
  }
  if ((t & 63) == 0) {
#pragma unroll
    for (int s5 = 0; s5 < 5; ++s5) sc[s5 * 4 + (t >> 6)] = v[s5];
  }
  __syncthreads();
  if (t == 0) {
    float S[5];
#pragma unroll
    for (int s5 = 0; s5 < 5; ++s5)
      S[s5] = sc[s5 * 4] + sc[s5 * 4 + 1] + sc[s5 * 4 + 2] + sc[s5 * 4 + 3];
    const float rep    = S[0] / (float)(B_ * N_ * 4);
    const float smooth = S[1] / (float)(B_ * N_);
    const float cd     = (S[2] + S[3]) / (float)(B_ * N_);
    const float cov    = S[4] / (float)(B_ * K_);
    const float total  = 1.0f * cd + 0.01f * rep + 0.005f * smooth + 0.1f * cov;
    out[0] = total;
    out[1] = cd;
    out[2] = rep;
    out[3] = smooth;
    out[4] = cov;
  }
}

extern "C" void kernel_launch(void* const* d_in, const int* in_sizes, int n_in,
                              void* d_out, int out_size, void* d_ws, size_t ws_size,
                              hipStream_t stream) {
  const float* pred    = (const float*)d_in[0];  // [4,4096,3]
  const float* gt      = (const float*)d_in[1];  // [4,4096,3]
  const float* partial = (const float*)d_in[2];  // [4,2048,3]
  float* out = (float*)d_out;                    // 5 scalars
  float* ws  = (float*)d_ws;                     // >= 1664 floats, all written each call

  fused_loss<<<GRID, TPB, 0, stream>>>(pred, gt, partial, ws);
  finalize<<<1, TPB, 0, stream>>>(ws, out);
}

// Round 4
// 97.339 us; speedup vs baseline: 1.1069x; 1.0022x over previous
//
#include <hip/hip_runtime.h>
#include <float.h>
#include <math.h>

// Problem constants (from reference setup_inputs)
#define B_ 4
#define N_ 4096
#define K_ 2048
#define TPB 256

// R11: balanced grid + double-buffered tiles.
//   - coverage folded INTO role-3 blocks (same pred tiles; +1% VALU, zero
//     extra LDS traffic; kills 128 blocks + 67MB of LDS reads)
//   - grid = 512 role-3 + 512 chamfer = 1024 = exactly 4 blocks/CU
//     (VGPR residency limit), round-robin gives each CU 2+2 -> balanced
//   - LDS tile double-buffered: 1 barrier/tile (was 2), staging overlapped
//   role-3: 2 rows/thread (8 B LDS/pair) + 1 coverage row/thread
//   chamfer: 8 rows/thread (2 B LDS/pair)
#define R3_NB 512
#define CD_NB 256
#define GRID (R3_NB + 2 * CD_NB)  // 1024

// ws partial-sum layout (floats); every slot written every call -> no zeroing
#define WS_REP 0      // 512
#define WS_SMO 512    // 512
#define WS_CD1 1024   // 256
#define WS_CD2 1280   // 256
#define WS_COV 1536   // 512 (one per role-3 block)

// role-3 tile: 16 groups x 65 float4 (16-lane broadcast, disjoint 4-bank
// ranges per wave). chamfer tile: 32 groups x 33 float4 (8-lane broadcast,
// banks 4g mod 32 -> disjoint ranges, conflict-free).
#define GPAD3 65
#define R3_BUF 1040   // f4 per buffer (16*65)
#define GPADM 33
#define CD_BUF 1056   // f4 per buffer (32*33)
// role-3 epilogue areas (overlaid on buffers after the last tile barrier):
// merge lists 32 rows x 144 = [0..4608), aa [4608..4640), cov [4640..4912)
#define AA_OFF 4608
#define COV_OFF 4640
// smem: max(2*1040*4, 2*1056*4) = 8448 floats = 33792 B
#define SMEM_F 8448

__device__ inline float wave_sum(float v) {
#pragma unroll
  for (int off = 32; off > 0; off >>= 1) v += __shfl_down(v, off, 64);
  return v;
}

__device__ inline void ce_asc(float& a, float& b) {
  float lo = fminf(a, b), hi = fmaxf(a, b);
  a = lo; b = hi;
}
__device__ inline void ce_desc(float& a, float& b) {
  float lo = fminf(a, b), hi = fmaxf(a, b);
  a = hi; b = lo;
}

// Batcher odd-even mergesort of 8, DESCENDING: 19 CEs (validated R6)
__device__ inline void bsort8_desc(float (&v)[8]) {
#define CE(i, j) ce_desc(v[i], v[j])
  CE(0,1); CE(2,3); CE(4,5); CE(6,7);
  CE(0,2); CE(1,3); CE(4,6); CE(5,7);
  CE(1,2); CE(5,6);
  CE(0,4); CE(1,5); CE(2,6); CE(3,7);
  CE(2,4); CE(3,5);
  CE(1,2); CE(3,4); CE(5,6);
#undef CE
}

// bitonic 8-sequence cleanup to ascending (3 stages, 12 CEs)
__device__ inline void bitonic_merge8_asc(float (&v)[8]) {
#pragma unroll
  for (int j = 4; j > 0; j >>= 1) {
#pragma unroll
    for (int i = 0; i < 8; ++i) {
      int ixj = i ^ j;
      if (ixj > i) ce_asc(v[i], v[ixj]);
    }
  }
}

// bitonic 16-sequence cleanup to ascending (4 stages, 32 CEs)
__device__ inline void bitonic_merge16_asc(float (&v)[16]) {
#pragma unroll
  for (int j = 8; j > 0; j >>= 1) {
#pragma unroll
    for (int i = 0; i < 16; ++i) {
      int ixj = i ^ j;
      if (ixj > i) ce_asc(v[i], v[ixj]);
    }
  }
}

// L1: two ascending 8-lists at A[0..7] and A[9..16] -> full ascending 16 at
// A[0..15] (in place; task region is 18 floats, reads complete before writes).
__device__ inline void fullmerge8_inplace(float* A) {
  float m[16];
#pragma unroll
  for (int i = 0; i < 8; ++i) m[i] = A[i];
#pragma unroll
  for (int i = 0; i < 8; ++i) m[8 + i] = A[9 + 7 - i];  // asc then desc = bitonic
  bitonic_merge16_asc(m);
#pragma unroll
  for (int i = 0; i < 16; ++i) A[i] = m[i];
}

// merge two ascending-16 lists -> 16 smallest ascending, stored to A
__device__ inline void keep16_lds(float* A, const float* Bl) {
  float m[16];
#pragma unroll
  for (int i = 0; i < 16; ++i) m[i] = fminf(A[i], Bl[15 - i]);
  bitonic_merge16_asc(m);
#pragma unroll
  for (int i = 0; i < 16; ++i) A[i] = m[i];
}

// Distances via s' = |c|^2 - 2 a.c (LDS tile stores (x,y,z,|c|^2));
// |a|^2 added back after selection (monotone shift). Validated since R3.
// Role-3 keeps per-thread top-8 over 256 cands (16 threads/row): row top-8
// provably exact; ranks 9-16 exact unless one thread holds >=9 of the row's
// top-16 (P~3e-6/row, error ~1e-7 if fired). Unchanged since R7.
__global__ __launch_bounds__(TPB, 3) void fused_loss(const float* __restrict__ pred,
                                                     const float* __restrict__ gt,
                                                     const float* __restrict__ partial,
                                                     float* __restrict__ ws) {
  __shared__ __align__(16) float smem_f[SMEM_F];
  float4* tile = reinterpret_cast<float4*>(smem_f);

  const int blk = blockIdx.x;
  const int t = threadIdx.x;

  if (blk < R3_NB) {
    // ======= role 3: pred self top-16 (+ folded coverage) =======
    // 32 pred rows/block (2/thread) + 16 partial rows/block (1/thread,
    // min over the SAME staged pred tiles).
    const int r = t & 15;        // row slot
    const int g = t >> 4;        // column group (16 groups x 64 cols)
    const int base = g * GPAD3;
    const int rid = blk;
    const int b = rid >> 7;              // 128 blocks/batch
    const int row0 = (rid & 127) * 32;
    const int prow0 = (rid & 127) * 16;  // partial rows (2048/batch/128)
    const size_t cbase = (size_t)b * N_ * 3;

    float nx[2], ny[2], nz[2], aa2[2];
#pragma unroll
    for (int q = 0; q < 2; ++q) {
      const size_t p = cbase + (size_t)(row0 + q * 16 + r) * 3;
      const float x = pred[p], y = pred[p + 1], z = pred[p + 2];
      aa2[q] = fmaf(x, x, fmaf(y, y, z * z));
      nx[q] = -2.f * x; ny[q] = -2.f * y; nz[q] = -2.f * z;
    }
    // coverage row coeffs (one partial row per thread, shared by the 16
    // threads with equal r; each covers its own group's columns)
    float cnx, cny, cnz, caa;
    {
      const size_t p = ((size_t)b * K_ + prow0 + r) * 3;
      const float x = partial[p], y = partial[p + 1], z = partial[p + 2];
      caa = fmaf(x, x, fmaf(y, y, z * z));
      cnx = -2.f * x; cny = -2.f * y; cnz = -2.f * z;
    }
    float cm0 = FLT_MAX, cm1 = FLT_MAX;

    float t8[2][8];
#pragma unroll
    for (int q = 0; q < 2; ++q)
#pragma unroll
      for (int i = 0; i < 8; ++i) t8[q][i] = FLT_MAX;

    // prologue: stage tile0, prefetch tile1 into regs
    float px[4], py[4], pz[4];
#pragma unroll
    for (int k = 0; k < 4; ++k) {
      const size_t p = cbase + 3 * (size_t)(t + k * 256);
      px[k] = pred[p]; py[k] = pred[p + 1]; pz[k] = pred[p + 2];
    }
#pragma unroll
    for (int k = 0; k < 4; ++k) {
      const int i = t + k * 256;
      tile[(i >> 6) * GPAD3 + (i & 63)] =
          make_float4(px[k], py[k], pz[k],
                      fmaf(px[k], px[k], fmaf(py[k], py[k], pz[k] * pz[k])));
    }
#pragma unroll
    for (int k = 0; k < 4; ++k) {  // WAR on px: ds_write above consumes first
      const size_t p = cbase + 3 * (size_t)(1024 + t + k * 256);
      px[k] = pred[p]; py[k] = pred[p + 1]; pz[k] = pred[p + 2];
    }
    __syncthreads();

#pragma unroll 1
    for (int T = 0; T < 4; ++T) {
      const float4* tb = tile + (T & 1) * R3_BUF;

#pragma unroll 1
      for (int jb = 0; jb < 64; jb += 8) {
        float4 c[8];
#pragma unroll
        for (int u = 0; u < 8; ++u) c[u] = tb[base + jb + u];
#pragma unroll
        for (int q = 0; q < 2; ++q) {
          float s[8];
#pragma unroll
          for (int u = 0; u < 8; ++u)
            s[u] = fmaf(nx[q], c[u].x, fmaf(ny[q], c[u].y, fmaf(nz[q], c[u].z, c[u].w)));
          bsort8_desc(s);
          // t8 asc + s desc: elementwise min = bitonic holding 8 smallest of 16
#pragma unroll
          for (int i = 0; i < 8; ++i) t8[q][i] = fminf(t8[q][i], s[i]);
          bitonic_merge8_asc(t8[q]);
        }
        // folded coverage: 2 independent fmin chains over the same c[]
#pragma unroll
        for (int u = 0; u < 8; u += 2) {
          cm0 = fminf(cm0, fmaf(cnx, c[u].x, fmaf(cny, c[u].y, fmaf(cnz, c[u].z, c[u].w))));
          cm1 = fminf(cm1, fmaf(cnx, c[u + 1].x, fmaf(cny, c[u + 1].y, fmaf(cnz, c[u + 1].z, c[u + 1].w))));
        }
      }

      if (T < 3) {  // stage tile T+1 (regs -> other buffer), prefetch T+2
        float4* nb = tile + ((T + 1) & 1) * R3_BUF;
#pragma unroll
        for (int k = 0; k < 4; ++k) {
          const int i = t + k * 256;
          nb[(i >> 6) * GPAD3 + (i & 63)] =
              make_float4(px[k], py[k], pz[k],
                          fmaf(px[k], px[k], fmaf(py[k], py[k], pz[k] * pz[k])));
        }
        if (T < 2) {
#pragma unroll
          for (int k = 0; k < 4; ++k) {
            const size_t p = cbase + 3 * (size_t)((T + 2) * 1024 + t + k * 256);
            px[k] = pred[p]; py[k] = pred[p + 1]; pz[k] = pred[p + 2];
          }
        }
      }
      __syncthreads();
    }

    // ---- epilogue: merge lists + coverage reduce (overlaid on buffers) ----
#pragma unroll
    for (int q = 0; q < 2; ++q) {
      const int rl = q * 16 + r;
#pragma unroll
      for (int i = 0; i < 8; ++i) smem_f[rl * 144 + g * 9 + i] = t8[q][i];
    }
    if (g == 0) {
#pragma unroll
      for (int q = 0; q < 2; ++q) smem_f[AA_OFF + q * 16 + r] = aa2[q];
    }
    smem_f[COV_OFF + r * 17 + g] = fminf(cm0, cm1);
    __syncthreads();
    // L1: 256 pair-merges (8+8 -> full 16, in place), 1 per thread
    fullmerge8_inplace(&smem_f[(t >> 3) * 144 + (t & 7) * 18]);
    __syncthreads();
    if (t < 128) {  // L2: 128 keep-16 merges
      float* A = &smem_f[(t >> 2) * 144 + (t & 3) * 36];
      keep16_lds(A, A + 18);
    } else if (t < 192) {  // wave 2: coverage cross-group reduce (free slot)
      const int lane = t - 128;
      float d = 0.f;
      if (lane < 16) {
        float mm = FLT_MAX;
#pragma unroll
        for (int k = 0; k < 16; ++k) mm = fminf(mm, smem_f[COV_OFF + lane * 17 + k]);
        d = sqrtf(fmaxf(mm + caa, 1e-12f));  // caa matches row: r == lane here
      }
      d = wave_sum(d);
      if (t == 128) ws[WS_COV + rid] = d;
    }
    __syncthreads();
    if (t < 64) {  // L3: 64 keep-16 merges
      float* A = &smem_f[(t >> 1) * 144 + (t & 1) * 72];
      keep16_lds(A, A + 36);
    }
    __syncthreads();
    if (t < 64) {  // L4 + stats: 32 rows on wave 0 (lanes 32-63 contribute 0)
      float rep_acc = 0.f, var_acc = 0.f;
      if (t < 32) {
        const float* A = &smem_f[t * 144];
        const float* Bl = A + 72;
        float f[16];
#pragma unroll
        for (int i = 0; i < 16; ++i) f[i] = fminf(A[i], Bl[15 - i]);
        bitonic_merge16_asc(f);
        const float aar = smem_f[AA_OFF + t];
        float d16[16], sum = 0.f;
#pragma unroll
        for (int i = 0; i < 16; ++i) {
          d16[i] = sqrtf(fmaxf(f[i] + aar, 1e-12f));  // self -> 1e-6, rank 0
          sum += d16[i];
        }
        const float mean = sum * 0.0625f;
        float var = 0.f;
#pragma unroll
        for (int i = 0; i < 16; ++i) {
          float e = d16[i] - mean;
          var = fmaf(e, e, var);
        }
        var_acc = var * (1.f / 15.f);  // unbiased
#pragma unroll
        for (int i = 1; i <= 4; ++i) rep_acc += fmaxf(0.01f - d16[i], 0.f);
      }
      const float rs = wave_sum(rep_acc);
      const float vs = wave_sum(var_acc);
      if (t == 0) {
        ws[WS_REP + rid] = rs;
        ws[WS_SMO + rid] = vs;
      }
    }
  } else {
    // ======= chamfer roles: pred->gt and gt->pred =======
    // 64 rows/block, 8 rows/thread: each float4 LDS read feeds 8 rows.
    const int mid = blk - R3_NB;
    const int role = (mid < CD_NB) ? 0 : 1;
    const int rel = (role == 0) ? mid : mid - CD_NB;

    const int r = t & 7;         // row slot (8)
    const int g = t >> 3;        // column group (32 groups x 32 cols)
    const int base = g * GPADM;

    const int b = rel >> 6;               // 64 blocks/batch
    const int row0 = (rel & 63) * 64;

    const float* colsrc = (role == 0) ? gt : pred;
    const float* rowsrc = (role == 1) ? gt : pred;
    const size_t cbase = (size_t)b * N_ * 3;

    float nx[8], ny[8], nz[8], aa8[8];
#pragma unroll
    for (int q = 0; q < 8; ++q) {
      const size_t p = ((size_t)b * N_ + row0 + q * 8 + r) * 3;
      const float x = rowsrc[p], y = rowsrc[p + 1], z = rowsrc[p + 2];
      aa8[q] = fmaf(x, x, fmaf(y, y, z * z));
      nx[q] = -2.f * x; ny[q] = -2.f * y; nz[q] = -2.f * z;
    }

    float m[32];  // chain (q, col&3): 32 independent fmin chains
#pragma unroll
    for (int i = 0; i < 32; ++i) m[i] = FLT_MAX;

    // prologue: stage tile0, prefetch tile1 into regs
    float px[4], py[4], pz[4];
#pragma unroll
    for (int k = 0; k < 4; ++k) {
      const size_t p = cbase + 3 * (size_t)(t + k * 256);
      px[k] = colsrc[p]; py[k] = colsrc[p + 1]; pz[k] = colsrc[p + 2];
    }
#pragma unroll
    for (int k = 0; k < 4; ++k) {
      const int i = t + k * 256;
      tile[(i >> 5) * GPADM + (i & 31)] =
          make_float4(px[k], py[k], pz[k],
                      fmaf(px[k], px[k], fmaf(py[k], py[k], pz[k] * pz[k])));
    }
#pragma unroll
    for (int k = 0; k < 4; ++k) {
      const size_t p = cbase + 3 * (size_t)(1024 + t + k * 256);
      px[k] = colsrc[p]; py[k] = colsrc[p + 1]; pz[k] = colsrc[p + 2];
    }
    __syncthreads();

#pragma unroll 1
    for (int T = 0; T < 4; ++T) {
      const float4* tb = tile + (T & 1) * CD_BUF;

#pragma unroll 4
      for (int j = 0; j < 32; j += 4) {
        const float4 c0 = tb[base + j + 0];
        const float4 c1 = tb[base + j + 1];
        const float4 c2 = tb[base + j + 2];
        const float4 c3 = tb[base + j + 3];
#pragma unroll
        for (int q = 0; q < 8; ++q) {
          m[q * 4 + 0] = fminf(m[q * 4 + 0], fmaf(nx[q], c0.x, fmaf(ny[q], c0.y, fmaf(nz[q], c0.z, c0.w))));
          m[q * 4 + 1] = fminf(m[q * 4 + 1], fmaf(nx[q], c1.x, fmaf(ny[q], c1.y, fmaf(nz[q], c1.z, c1.w))));
          m[q * 4 + 2] = fminf(m[q * 4 + 2], fmaf(nx[q], c2.x, fmaf(ny[q], c2.y, fmaf(nz[q], c2.z, c2.w))));
          m[q * 4 + 3] = fminf(m[q * 4 + 3], fmaf(nx[q], c3.x, fmaf(ny[q], c3.y, fmaf(nz[q], c3.z, c3.w))));
        }
      }

      if (T < 3) {
        float4* nb = tile + ((T + 1) & 1) * CD_BUF;
#pragma unroll
        for (int k = 0; k < 4; ++k) {
          const int i = t + k * 256;
          nb[(i >> 5) * GPADM + (i & 31)] =
              make_float4(px[k], py[k], pz[k],
                          fmaf(px[k], px[k], fmaf(py[k], py[k], pz[k] * pz[k])));
        }
        if (T < 2) {
#pragma unroll
          for (int k = 0; k < 4; ++k) {
            const size_t p = cbase + 3 * (size_t)((T + 2) * 1024 + t + k * 256);
            px[k] = colsrc[p]; py[k] = colsrc[p + 1]; pz[k] = colsrc[p + 2];
          }
        }
      }
      __syncthreads();
    }

#pragma unroll
    for (int q = 0; q < 8; ++q) {
      // +aa[q] is constant per row: commutes with the cross-group min
      const float mm = fminf(fminf(m[q * 4 + 0], m[q * 4 + 1]),
                             fminf(m[q * 4 + 2], m[q * 4 + 3])) + aa8[q];
      smem_f[(q * 8 + r) * GPADM + g] = mm;  // stride 33: reads 2-way (free)
    }
    __syncthreads();
    if (t < 64) {  // wave 0: one row per lane
      float mm = FLT_MAX;
#pragma unroll
      for (int k = 0; k < 32; ++k) mm = fminf(mm, smem_f[t * GPADM + k]);
      float d = sqrtf(fmaxf(mm, 1e-12f));
      d = wave_sum(d);
      if (t == 0) {
        const int slot = (role == 0) ? WS_CD1 + rel : WS_CD2 + rel;
        ws[slot] = d;
      }
    }
  }
}

__global__ void finalize(const float* __restrict__ ws, float* __restrict__ out) {
  __shared__ float sc[20];
  const int t = threadIdx.x;
  const int offs[5] = {WS_REP, WS_SMO, WS_CD1, WS_CD2, WS_COV};
  const int lens[5] = {512, 512, 256, 256, 512};
  float v[5];
#pragma unroll
  for (int s5 = 0; s5 < 5; ++s5) {
    float s = 0.f;
    for (int i = t; i < lens[s5]; i += TPB) s += ws[offs[s5] + i];
    v[s5] = wave_sum(s);
  }
  if ((t & 63) == 0) {
#pragma unroll
    for (int s5 = 0; s5 < 5; ++s5) sc[s5 * 4 + (t >> 6)] = v[s5];
  }
  __syncthreads();
  if (t == 0) {
    float S[5];
#pragma unroll
    for (int s5 = 0; s5 < 5; ++s5)
      S[s5] = sc[s5 * 4] + sc[s5 * 4 + 1] + sc[s5 * 4 + 2] + sc[s5 * 4 + 3];
    const float rep    = S[0] / (float)(B_ * N_ * 4);
    const float smooth = S[1] / (float)(B_ * N_);
    const float cd     = (S[2] + S[3]) / (float)(B_ * N_);
    const float cov    = S[4] / (float)(B_ * K_);
    const float total  = 1.0f * cd + 0.01f * rep + 0.005f * smooth + 0.1f * cov;
    out[0] = total;
    out[1] = cd;
    out[2] = rep;
    out[3] = smooth;
    out[4] = cov;
  }
}

extern "C" void kernel_launch(void* const* d_in, const int* in_sizes, int n_in,
                              void* d_out, int out_size, void* d_ws, size_t ws_size,
                              hipStream_t stream) {
  const float* pred    = (const float*)d_in[0];  // [4,4096,3]
  const float* gt      = (const float*)d_in[1];  // [4,4096,3]
  const float* partial = (const float*)d_in[2];  // [4,2048,3]
  float* out = (float*)d_out;                    // 5 scalars
  float* ws  = (float*)d_ws;                     // >= 2048 floats, all written each call

  fused_loss<<<GRID, TPB, 0, stream>>>(pred, gt, partial, ws);
  finalize<<<1, TPB, 0, stream>>>(ws, out);
}